// Round 4
// baseline (619.586 us; speedup 1.0000x reference)
//
#include <hip/hip_runtime.h>

// ---- problem dims (fixed) ----
#define TT 2048   // tokens = B*S
#define HH 1024   // hidden
#define FF 4096   // intermediate
#define EE 8      // experts
#define EROWS 640      // fixed row slots per expert (mean 512, sigma ~20 -> 6.5 sigma headroom)
#define ROWS_CAP 5120  // 8 * 640
#define KSPLIT2 4      // gemm2 split-K factor

typedef __bf16 bf16;
typedef bf16 bf16x8 __attribute__((ext_vector_type(8)));
typedef bf16 bf16x4 __attribute__((ext_vector_type(4)));
typedef bf16 bf16x2 __attribute__((ext_vector_type(2)));
typedef float floatx4 __attribute__((ext_vector_type(4)));

// ---- workspace layout (bytes) ----  (no transposed-weight buffers anymore)
#define OFF_XG   ((size_t)0)                       // [ROWS_CAP][H] bf16 = 10485760
#define OFF_H    (OFF_XG  + (size_t)10485760)      // [ROWS_CAP][F] bf16 = 41943040
#define OFF_Y    (OFF_H   + (size_t)41943040)      // [KSPLIT2][ROWS_CAP][H] bf16 = 41943040
#define OFF_CNT  (OFF_Y   + (size_t)41943040)      // int[8] (256B slot)
#define OFF_TKW  (OFF_CNT + (size_t)256)           // float[T][2]
#define OFF_ROW  (OFF_TKW + (size_t)16384)         // int[T][2] row index per (token,slot)

// async global->LDS, 16B per lane; LDS dest is wave-uniform base + lane*16
__device__ __forceinline__ void gload16(const bf16* g, bf16* l) {
    __builtin_amdgcn_global_load_lds((const __attribute__((address_space(1))) void*)g,
                                     (__attribute__((address_space(3))) void*)l, 16, 0, 0);
}

// ---- fused router + gather (verified body) ----
__global__ __launch_bounds__(256) void router_gather(const float* __restrict__ x,
                                                     const float* __restrict__ gw,
                                                     const float* __restrict__ gb,
                                                     int* __restrict__ counts,
                                                     bf16* __restrict__ xg,
                                                     int* __restrict__ rowOf,
                                                     float* __restrict__ tkw) {
    const int wid = blockIdx.x * 4 + (threadIdx.x >> 6);
    const int lane = threadIdx.x & 63;
    for (int t = wid; t < TT; t += 1024) {
        const float* xr = x + (size_t)t * HH;
        float xf[16];
        double acc[EE];
#pragma unroll
        for (int e = 0; e < EE; ++e) acc[e] = 0.0;
#pragma unroll
        for (int i = 0; i < 16; ++i) {
            const int h = lane + i * 64;
            const float xv = xr[h];
            xf[i] = xv;
            const float* g = gw + (size_t)h * EE;
            floatx4 g0 = *(const floatx4*)&g[0];
            floatx4 g1 = *(const floatx4*)&g[4];
            const double xd = (double)xv;
            acc[0] += xd * (double)g0[0]; acc[1] += xd * (double)g0[1];
            acc[2] += xd * (double)g0[2]; acc[3] += xd * (double)g0[3];
            acc[4] += xd * (double)g1[0]; acc[5] += xd * (double)g1[1];
            acc[6] += xd * (double)g1[2]; acc[7] += xd * (double)g1[3];
        }
#pragma unroll
        for (int e = 0; e < EE; ++e) {
            double v = acc[e];
            for (int s = 32; s > 0; s >>= 1) v += __shfl_xor(v, s, 64);
            acc[e] = v + (double)gb[e];
        }
        int row1 = 0, row2 = 0;
        if (lane == 0) {
            int i1 = 0; double v1 = acc[0];
            for (int e = 1; e < EE; ++e) if (acc[e] > v1) { v1 = acc[e]; i1 = e; }
            int i2 = -1; double v2 = -1e300;
            for (int e = 0; e < EE; ++e) if (e != i1 && acc[e] > v2) { v2 = acc[e]; i2 = e; }
            double wa = 1.0 / (1.0 + exp(v2 - v1));   // renormalized softmax of top-2
            double wb = 1.0 - wa;
            int r1 = atomicAdd(&counts[i1], 1); if (r1 > EROWS - 1) r1 = EROWS - 1;
            int r2 = atomicAdd(&counts[i2], 1); if (r2 > EROWS - 1) r2 = EROWS - 1;
            row1 = i1 * EROWS + r1;
            row2 = i2 * EROWS + r2;
            rowOf[t * 2 + 0] = row1; rowOf[t * 2 + 1] = row2;
            tkw[t * 2 + 0] = (float)wa; tkw[t * 2 + 1] = (float)wb;
        }
        row1 = __shfl(row1, 0, 64);
        row2 = __shfl(row2, 0, 64);
        bf16* d1 = xg + (size_t)row1 * HH;
        bf16* d2 = xg + (size_t)row2 * HH;
#pragma unroll
        for (int i = 0; i < 16; ++i) {
            const bf16 v = (bf16)xf[i];
            d1[lane + i * 64] = v;          // 2B/lane, lanes contiguous -> coalesced
            d2[lane + i * 64] = v;
        }
    }
}

// ================= GEMM core: 128M x 256N x 32K tile, 2-stage LDS double-buffer ========
// A: [M][LDA] bf16 (K-contiguous) staged via global_load_lds (linear, k-oct XOR layout).
// B: ORIGINAL fp32 weights [K][LDB] (n-contiguous) — transposed+converted during staging:
//   thread t owns k-pair kp=t&15 (k=2kp,2kp+1) and n-block nb=t>>4 (16 n's).
//   Loads 8x float4 coalesced; packs bf16x2 along k; ds_write_b32 into the SAME
//   physical LDS layout as before (k-oct g stored at g ^ ((n>>1)&3)) -> frag reads
//   keep the proven zero-conflict foff pattern. Write conflicts: 4-way (acceptable).
// Plain __syncthreads() per K-step (compiler-managed waitcnts, m97 scheme).
// LDS: 2*(8KB A + 16KB B) = 48 KB -> 2 blocks/CU.

#define B_LOAD(KT) do {                                                                     \
        const float* bp = bsrc + (size_t)(KT) * 32 * LDB;                                   \
        _Pragma("unroll") for (int q = 0; q < 4; ++q) {                                     \
            bv[q]     = *(const floatx4*)(bp + q * 4);                                      \
            bv[4 + q] = *(const floatx4*)(bp + LDB + q * 4);                                \
        }                                                                                   \
    } while (0)

#define B_WRITE(ST) do {                                                                    \
        bf16* bb = &Bs[ST][(unsigned)nb * 512 + ((unsigned)(kp & 3) << 1)];                 \
        const int bq = kp >> 2;                                                             \
        _Pragma("unroll") for (int j = 0; j < 16; ++j) {                                    \
            bf16x2 p;                                                                       \
            p[0] = (bf16)bv[j >> 2][j & 3];                                                 \
            p[1] = (bf16)bv[4 + (j >> 2)][j & 3];                                           \
            *(bf16x2*)(bb + j * 32 + ((unsigned)(bq ^ ((j >> 1) & 3)) << 3)) = p;           \
        }                                                                                   \
    } while (0)

#define A_STAGE(KT, ST) do {                                                                \
        const int kb = (KT) * 32;                                                           \
        gload16(Ab + agadr0 + kb, (bf16*)((char*)As[ST] + ldsw));                           \
        gload16(Ab + agadr1 + kb, (bf16*)((char*)As[ST] + 4096u + ldsw));                   \
    } while (0)

#define GEMM_BODY(EPILOGUE)                                                                 \
    __shared__ bf16 As[2][128 * 32];                                                        \
    __shared__ bf16 Bs[2][256 * 32];                                                        \
    const int tid = threadIdx.x;                                                            \
    const int lane = tid & 63, wave = tid >> 6;                                             \
    const int lrow = lane & 15, lq = lane >> 4;                                             \
    const int m_w = (wave & 1) << 6, n_w = (wave >> 1) << 7;                                \
    const unsigned foff = (unsigned)((lq ^ ((lrow >> 1) & 3)) << 3);                        \
    floatx4 acc[4][8];                                                                      \
    _Pragma("unroll") for (int i = 0; i < 4; ++i)                                           \
        _Pragma("unroll") for (int j = 0; j < 8; ++j)                                       \
            acc[i][j] = (floatx4){0.f, 0.f, 0.f, 0.f};                                      \
    size_t agadr0, agadr1;                                                                  \
    {                                                                                       \
        int c0 = tid, ar0 = c0 >> 2, ak0 = (c0 & 3) ^ ((ar0 >> 1) & 3);                     \
        agadr0 = (size_t)ar0 * LDA + (size_t)ak0 * 8;                                       \
        int c1 = tid + 256, ar1 = c1 >> 2, ak1 = (c1 & 3) ^ ((ar1 >> 1) & 3);               \
        agadr1 = (size_t)ar1 * LDA + (size_t)ak1 * 8;                                       \
    }                                                                                       \
    const unsigned ldsw = (unsigned)((tid & ~63) << 4); /* wave*1024 bytes */               \
    const int kp = tid & 15, nb = tid >> 4;                                                 \
    const float* bsrc = Bf + (size_t)(2 * kp) * LDB + (size_t)nb * 16;                      \
    floatx4 bv[8];                                                                          \
    /* prologue: stage tile 0 into buffer 0 */                                              \
    B_LOAD(0);                                                                              \
    A_STAGE(0, 0);                                                                          \
    B_WRITE(0);                                                                             \
    __syncthreads();                                                                        \
    for (int kt = 0; kt < NK; ++kt) {                                                       \
        const int cb = kt & 1;                                                              \
        if (kt + 1 < NK) {                                                                  \
            B_LOAD(kt + 1);          /* fp32 loads in flight under compute */               \
            A_STAGE(kt + 1, cb ^ 1); /* async DMA to next buffer */                         \
        }                                                                                   \
        bf16x8 af[4], bfr[8];                                                               \
        _Pragma("unroll") for (int i = 0; i < 4; ++i) {                                     \
            int m = m_w + i * 16 + lrow;                                                    \
            af[i] = *(const bf16x8*)&As[cb][(unsigned)m * 32 + foff];                       \
        }                                                                                   \
        _Pragma("unroll") for (int j = 0; j < 8; ++j) {                                     \
            int n = n_w + j * 16 + lrow;                                                    \
            bfr[j] = *(const bf16x8*)&Bs[cb][(unsigned)n * 32 + foff];                      \
        }                                                                                   \
        _Pragma("unroll") for (int i = 0; i < 4; ++i)                                       \
            _Pragma("unroll") for (int j = 0; j < 8; ++j)                                   \
                acc[i][j] = __builtin_amdgcn_mfma_f32_16x16x32_bf16(af[i], bfr[j],          \
                                                                    acc[i][j], 0, 0, 0);    \
        if (kt + 1 < NK) B_WRITE(cb ^ 1);                                                   \
        __syncthreads(); /* drains A-DMA (vmcnt) + B-writes (lgkm) for next buffer */       \
    }                                                                                       \
    EPILOGUE

// ---- GEMM1: h = relu(xg @ w1[e] + b1[e]) -> bf16 ----
__global__ __launch_bounds__(256, 2) void gemm1_kernel(const bf16* __restrict__ A,
                                                       const float* __restrict__ W1,
                                                       const float* __restrict__ b1,
                                                       bf16* __restrict__ Hout,
                                                       const int* __restrict__ counts) {
    const int e = blockIdx.z, mt = blockIdx.y, nt = blockIdx.x;
    const int cnt = counts[e];
    if (mt * 128 >= cnt) return;
    const int row0 = e * EROWS + mt * 128;
    const int LDA = HH;            // A row stride (elements)
    const int LDB = FF;            // W1[k][n] row stride
    const int NK = HH / 32;
    const bf16*  Ab = A + (size_t)row0 * LDA;
    const float* Bf = W1 + (size_t)e * HH * FF + (size_t)nt * 256;

    GEMM_BODY({
        const float* bias = b1 + (size_t)e * FF + (size_t)nt * 256;
        bf16* Hb = Hout + (size_t)row0 * FF + (size_t)nt * 256;
        _Pragma("unroll") for (int j = 0; j < 8; ++j) {
            int col = n_w + j * 16 + lrow;
            float bv_ = bias[col];
            _Pragma("unroll") for (int i = 0; i < 4; ++i)
                _Pragma("unroll") for (int r = 0; r < 4; ++r) {
                    int mrow = m_w + i * 16 + (lq << 2) + r;  // C/D: col=lane&15, row=quad*4+reg
                    float v = acc[i][j][r] + bv_;
                    Hb[(size_t)mrow * FF + col] = (bf16)(v > 0.f ? v : 0.f);
                }
        }
    })
}

// ---- GEMM2: y[ks][row] = h-slice @ w2-slice (+b2 at ks==0) -> bf16 ----
__global__ __launch_bounds__(256, 2) void gemm2_kernel(const bf16* __restrict__ Hin,
                                                       const float* __restrict__ W2,
                                                       const float* __restrict__ b2,
                                                       bf16* __restrict__ Y,
                                                       const int* __restrict__ counts) {
    const int e = blockIdx.z >> 2, ks = blockIdx.z & 3;
    const int mt = blockIdx.y, nt = blockIdx.x;
    const int cnt = counts[e];
    if (mt * 128 >= cnt) return;
    const int row0 = e * EROWS + mt * 128;
    const int KC = FF / KSPLIT2;           // 1024 per split
    const int LDA = FF;                    // H row stride (full K)
    const int LDB = HH;                    // W2[k][n] row stride
    const int NK = KC / 32;
    const bf16*  Ab = Hin + (size_t)row0 * LDA + ks * KC;
    const float* Bf = W2 + (size_t)e * FF * HH + (size_t)(ks * KC) * HH + (size_t)nt * 256;

    GEMM_BODY({
        const float* bias = b2 + (size_t)e * HH + (size_t)nt * 256;
        bf16* Yb = Y + ((size_t)ks * ROWS_CAP + row0) * HH + (size_t)nt * 256;
        _Pragma("unroll") for (int j = 0; j < 8; ++j) {
            int col = n_w + j * 16 + lrow;
            float bv_ = (ks == 0) ? bias[col] : 0.f;
            _Pragma("unroll") for (int i = 0; i < 4; ++i)
                _Pragma("unroll") for (int r = 0; r < 4; ++r) {
                    int mrow = m_w + i * 16 + (lq << 2) + r;
                    Yb[(size_t)mrow * HH + col] = (bf16)(acc[i][j][r] + bv_);
                }
        }
    })
}

// ---- combine: out[t] = sum_slot w_slot * sum_ks y[ks][row_slot] ----
__global__ __launch_bounds__(256) void combine_kernel(const bf16* __restrict__ Y,
                                                      const int* __restrict__ rowOf,
                                                      const float* __restrict__ tkw,
                                                      float* __restrict__ out) {
    const int t = blockIdx.x;
    const int tid = threadIdx.x;
    const int ra = rowOf[t * 2 + 0], rb = rowOf[t * 2 + 1];
    const float wa = tkw[t * 2 + 0], wb = tkw[t * 2 + 1];
    const int c = tid * 4;
    float acc[4] = {0.f, 0.f, 0.f, 0.f};
#pragma unroll
    for (int ks = 0; ks < KSPLIT2; ++ks) {
        bf16x4 a = *(const bf16x4*)&Y[((size_t)ks * ROWS_CAP + ra) * HH + c];
        bf16x4 b = *(const bf16x4*)&Y[((size_t)ks * ROWS_CAP + rb) * HH + c];
#pragma unroll
        for (int k = 0; k < 4; ++k) acc[k] += wa * (float)a[k] + wb * (float)b[k];
    }
    floatx4 o; o[0] = acc[0]; o[1] = acc[1]; o[2] = acc[2]; o[3] = acc[3];
    *(floatx4*)&out[(size_t)t * HH + c] = o;
}

extern "C" void kernel_launch(void* const* d_in, const int* in_sizes, int n_in,
                              void* d_out, int out_size, void* d_ws, size_t ws_size,
                              hipStream_t stream) {
    const float* x  = (const float*)d_in[0];
    const float* gw = (const float*)d_in[1];
    const float* gb = (const float*)d_in[2];
    const float* w1 = (const float*)d_in[3];
    const float* b1 = (const float*)d_in[4];
    const float* w2 = (const float*)d_in[5];
    const float* b2 = (const float*)d_in[6];
    float* out = (float*)d_out;
    char* ws = (char*)d_ws;

    bf16*  xg   = (bf16*)(ws + OFF_XG);
    bf16*  hbuf = (bf16*)(ws + OFF_H);
    bf16*  ybuf = (bf16*)(ws + OFF_Y);
    int*   cnts = (int*)(ws + OFF_CNT);
    float* tkw  = (float*)(ws + OFF_TKW);
    int*   rowOf= (int*)(ws + OFF_ROW);

    hipMemsetAsync(cnts, 0, 256, stream);

    // no transpose stage: GEMMs read original fp32 weights, transposing in-LDS
    router_gather<<<256, 256, 0, stream>>>(x, gw, gb, cnts, xg, rowOf, tkw);
    gemm1_kernel<<<dim3(FF / 256, 5, EE), 256, 0, stream>>>(xg, w1, b1, hbuf, cnts);
    gemm2_kernel<<<dim3(HH / 256, 5, EE * KSPLIT2), 256, 0, stream>>>(hbuf, w2, b2, ybuf, cnts);
    combine_kernel<<<TT, 256, 0, stream>>>(ybuf, rowOf, tkw, out);
}

// Round 5
// 587.002 us; speedup vs baseline: 1.0555x; 1.0555x over previous
//
#include <hip/hip_runtime.h>

// ---- problem dims (fixed) ----
#define TT 2048   // tokens = B*S
#define HH 1024   // hidden
#define FF 4096   // intermediate
#define EE 8      // experts
#define EROWS 640      // fixed row slots per expert (mean 512, sigma ~20 -> 6.5 sigma headroom)
#define ROWS_CAP 5120  // 8 * 640
#define KSPLIT2 4      // gemm2 split-K factor

typedef __bf16 bf16;
typedef bf16 bf16x8 __attribute__((ext_vector_type(8)));
typedef bf16 bf16x4 __attribute__((ext_vector_type(4)));
typedef bf16 bf16x2 __attribute__((ext_vector_type(2)));
typedef float floatx4 __attribute__((ext_vector_type(4)));

// ---- workspace layout (bytes) ----
#define OFF_W1T  ((size_t)0)                       // [E][F][H] bf16 = 67108864
#define OFF_W2T  (OFF_W1T + (size_t)67108864)      // [E][H][F] bf16 = 67108864
#define OFF_XG   (OFF_W2T + (size_t)67108864)      // [ROWS_CAP][H] bf16 = 10485760
#define OFF_H    (OFF_XG  + (size_t)10485760)      // [ROWS_CAP][F] bf16 = 41943040
#define OFF_CNT  (OFF_H   + (size_t)41943040)      // int[8] (256B slot)
#define OFF_TKW  (OFF_CNT + (size_t)256)           // float[T][2]
#define OFF_ROW  (OFF_TKW + (size_t)16384)         // int[T][2] row index per (token,slot)
// Y partials [KSPLIT2][ROWS_CAP][HH] bf16 = 41943040 bytes — ALIASES w1t region:
// w1t is dead after gemm1 (stream order: transposes -> gemm1 -> gemm2 -> combine).
#define OFF_Y    OFF_W1T

// async global->LDS, 16B per lane; LDS dest is wave-uniform base + lane*16
__device__ __forceinline__ void gload16(const bf16* g, bf16* l) {
    __builtin_amdgcn_global_load_lds((const __attribute__((address_space(1))) void*)g,
                                     (__attribute__((address_space(3))) void*)l, 16, 0, 0);
}

// raw workgroup barrier WITHOUT the __syncthreads() vmcnt(0) drain —
// execution sync only; we manage vmcnt ourselves (m139 technique).
__device__ __forceinline__ void raw_barrier() {
    asm volatile("s_barrier" ::: "memory");
}

// ---- transpose + fp32->bf16 convert: in[e][r][c] fp32 -> out[e][c][r] bf16 ----
__global__ __launch_bounds__(256) void transpose_cvt(const float* __restrict__ in,
                                                     bf16* __restrict__ out,
                                                     int R, int C) {
    __shared__ float tile[64][67];
    const int e  = blockIdx.z;
    const int r0 = blockIdx.y * 64, c0 = blockIdx.x * 64;
    const float* inp = in + (size_t)e * R * C;
    bf16* outp = out + (size_t)e * R * C;
    const int t = threadIdx.x;
    {
        const int lr = t >> 4;            // 0..15
        const int lc = (t & 15) << 2;     // 0..60 step 4
#pragma unroll
        for (int i = 0; i < 4; ++i) {
            int r = lr + i * 16;
            floatx4 v = __builtin_nontemporal_load(
                (const floatx4*)&inp[(size_t)(r0 + r) * C + c0 + lc]);
            tile[r][lc + 0] = v[0]; tile[r][lc + 1] = v[1];
            tile[r][lc + 2] = v[2]; tile[r][lc + 3] = v[3];
        }
    }
    __syncthreads();
    {
        const int c  = t >> 3;            // 0..31
        const int rq = (t & 7) << 3;      // 0..56 step 8
#pragma unroll
        for (int i = 0; i < 2; ++i) {
            int cc = c + i * 32;
            bf16x8 o;
#pragma unroll
            for (int k = 0; k < 8; ++k) o[k] = (bf16)tile[rq + k][cc];
            *(bf16x8*)&outp[(size_t)(c0 + cc) * R + r0 + rq] = o;
        }
    }
}

// ---- fused router + gather (verified body) ----
__global__ __launch_bounds__(256) void router_gather(const float* __restrict__ x,
                                                     const float* __restrict__ gw,
                                                     const float* __restrict__ gb,
                                                     int* __restrict__ counts,
                                                     bf16* __restrict__ xg,
                                                     int* __restrict__ rowOf,
                                                     float* __restrict__ tkw) {
    const int wid = blockIdx.x * 4 + (threadIdx.x >> 6);
    const int lane = threadIdx.x & 63;
    for (int t = wid; t < TT; t += 1024) {
        const float* xr = x + (size_t)t * HH;
        float xf[16];
        double acc[EE];
#pragma unroll
        for (int e = 0; e < EE; ++e) acc[e] = 0.0;
#pragma unroll
        for (int i = 0; i < 16; ++i) {
            const int h = lane + i * 64;
            const float xv = xr[h];
            xf[i] = xv;
            const float* g = gw + (size_t)h * EE;
            floatx4 g0 = *(const floatx4*)&g[0];
            floatx4 g1 = *(const floatx4*)&g[4];
            const double xd = (double)xv;
            acc[0] += xd * (double)g0[0]; acc[1] += xd * (double)g0[1];
            acc[2] += xd * (double)g0[2]; acc[3] += xd * (double)g0[3];
            acc[4] += xd * (double)g1[0]; acc[5] += xd * (double)g1[1];
            acc[6] += xd * (double)g1[2]; acc[7] += xd * (double)g1[3];
        }
#pragma unroll
        for (int e = 0; e < EE; ++e) {
            double v = acc[e];
            for (int s = 32; s > 0; s >>= 1) v += __shfl_xor(v, s, 64);
            acc[e] = v + (double)gb[e];
        }
        int row1 = 0, row2 = 0;
        if (lane == 0) {
            int i1 = 0; double v1 = acc[0];
            for (int e = 1; e < EE; ++e) if (acc[e] > v1) { v1 = acc[e]; i1 = e; }
            int i2 = -1; double v2 = -1e300;
            for (int e = 0; e < EE; ++e) if (e != i1 && acc[e] > v2) { v2 = acc[e]; i2 = e; }
            double wa = 1.0 / (1.0 + exp(v2 - v1));   // renormalized softmax of top-2
            double wb = 1.0 - wa;
            int r1 = atomicAdd(&counts[i1], 1); if (r1 > EROWS - 1) r1 = EROWS - 1;
            int r2 = atomicAdd(&counts[i2], 1); if (r2 > EROWS - 1) r2 = EROWS - 1;
            row1 = i1 * EROWS + r1;
            row2 = i2 * EROWS + r2;
            rowOf[t * 2 + 0] = row1; rowOf[t * 2 + 1] = row2;
            tkw[t * 2 + 0] = (float)wa; tkw[t * 2 + 1] = (float)wb;
        }
        row1 = __shfl(row1, 0, 64);
        row2 = __shfl(row2, 0, 64);
        bf16* d1 = xg + (size_t)row1 * HH;
        bf16* d2 = xg + (size_t)row2 * HH;
#pragma unroll
        for (int i = 0; i < 16; ++i) {
            const bf16 v = (bf16)xf[i];
            d1[lane + i * 64] = v;          // 2B/lane, lanes contiguous -> coalesced
            d2[lane + i * 64] = v;
        }
    }
}

// ================= GEMM core: 128M x 256N x 32K tile, 2-stage LDS double-buffer ========
// A: [M][K] bf16 (row-major, K contiguous). Bt: [N][K] bf16. 256 threads, 4 waves (2Mx2N).
// Dist-1 prefetch: issue 6 DMA loads for kt+1, wait vmcnt(6) for kt's 6, barrier, compute.
// Raw s_barrier (no vmcnt drain). LDS: 2*(8KB A + 16KB B) = 48 KB -> 3 blocks/CU:
// all 640 blocks resident in ONE round (was 72KB/2 blocks -> 512+128 tail round,
// occupancy 13.9% and latency-bound at MfmaUtil 18.8%).

#define STAGE(KT, ST) do {                                                                  \
        const int kb = (KT) * 32;                                                           \
        gload16(Ab + gadr[0] + kb, (bf16*)((char*)As[ST] + ldsw));                          \
        gload16(Ab + gadr[1] + kb, (bf16*)((char*)As[ST] + 4096u + ldsw));                  \
        gload16(Bb + gadr[2] + kb, (bf16*)((char*)Bs[ST] + ldsw));                          \
        gload16(Bb + gadr[3] + kb, (bf16*)((char*)Bs[ST] + 4096u + ldsw));                  \
        gload16(Bb + gadr[4] + kb, (bf16*)((char*)Bs[ST] + 8192u + ldsw));                  \
        gload16(Bb + gadr[5] + kb, (bf16*)((char*)Bs[ST] + 12288u + ldsw));                 \
    } while (0)

#define GEMM_BODY(EPILOGUE)                                                                 \
    __shared__ bf16 As[2][128 * 32];                                                        \
    __shared__ bf16 Bs[2][256 * 32];                                                        \
    const int tid = threadIdx.x;                                                            \
    const int lane = tid & 63, wave = tid >> 6;                                             \
    const int lrow = lane & 15, lq = lane >> 4;                                             \
    const int m_w = (wave & 1) << 6, n_w = (wave >> 1) << 7;                                \
    const unsigned foff = (unsigned)((lq ^ ((lrow >> 1) & 3)) << 3);                        \
    floatx4 acc[4][8];                                                                      \
    _Pragma("unroll") for (int i = 0; i < 4; ++i)                                           \
        _Pragma("unroll") for (int j = 0; j < 8; ++j)                                       \
            acc[i][j] = (floatx4){0.f, 0.f, 0.f, 0.f};                                      \
    int arow[6]; size_t gadr[6];                                                            \
    _Pragma("unroll") for (int s = 0; s < 6; ++s) {                                         \
        int c = tid + ((s < 2) ? s * 256 : (s - 2) * 256);                                  \
        int ar = c >> 2, ak = (c & 3) ^ ((ar >> 1) & 3);                                    \
        arow[s] = ar; gadr[s] = (size_t)ar * K + (size_t)ak * 8;                            \
    }                                                                                       \
    const unsigned ldsw = (unsigned)((tid & ~63) << 4); /* wave*1024 bytes */               \
    /* prologue: stage tile 0 into buffer 0 */                                              \
    STAGE(0, 0);                                                                            \
    for (int kt = 0; kt < NK; ++kt) {                                                       \
        const int cb = kt & 1;                                                              \
        raw_barrier();             /* all waves done computing from buf cb^1 (tile kt-1) */ \
        {                                                                                   \
            const int kn = (kt + 1 < NK) ? kt + 1 : NK - 1;  /* clamp: uniform vmcnt */     \
            STAGE(kn, cb ^ 1);                                                              \
        }                                                                                   \
        asm volatile("s_waitcnt vmcnt(6)" ::: "memory"); /* my tile-kt loads landed */      \
        raw_barrier();                                   /* everyone's landed */            \
        bf16x8 af[4], bfr[8];                                                               \
        _Pragma("unroll") for (int i = 0; i < 4; ++i) {                                     \
            int m = m_w + i * 16 + lrow;                                                    \
            af[i] = *(const bf16x8*)&As[cb][(unsigned)m * 32 + foff];                       \
        }                                                                                   \
        _Pragma("unroll") for (int j = 0; j < 8; ++j) {                                     \
            int n = n_w + j * 16 + lrow;                                                    \
            bfr[j] = *(const bf16x8*)&Bs[cb][(unsigned)n * 32 + foff];                      \
        }                                                                                   \
        _Pragma("unroll") for (int i = 0; i < 4; ++i)                                       \
            _Pragma("unroll") for (int j = 0; j < 8; ++j)                                   \
                acc[i][j] = __builtin_amdgcn_mfma_f32_16x16x32_bf16(af[i], bfr[j],          \
                                                                    acc[i][j], 0, 0, 0);    \
    }                                                                                       \
    asm volatile("s_waitcnt vmcnt(0)" ::: "memory"); /* drain DMA before endpgm */          \
    EPILOGUE

// ---- GEMM1: h = relu(xg @ w1[e] + b1[e]) -> bf16 ----
__global__ __launch_bounds__(256, 3) void gemm1_kernel(const bf16* __restrict__ A,
                                                       const bf16* __restrict__ Bt,
                                                       const float* __restrict__ b1,
                                                       bf16* __restrict__ Hout,
                                                       const int* __restrict__ counts) {
    const int e = blockIdx.z, mt = blockIdx.y, nt = blockIdx.x;
    const int cnt = counts[e];
    if (mt * 128 >= cnt) return;
    const int row0 = e * EROWS + mt * 128;
    const int K = HH;
    const int NK = K / 32;
    const bf16* Ab = A + (size_t)row0 * K;
    const bf16* Bb = Bt + ((size_t)e * FF + (size_t)nt * 256) * K;

    GEMM_BODY({
        const float* bias = b1 + (size_t)e * FF + (size_t)nt * 256;
        bf16* Hb = Hout + (size_t)row0 * FF + (size_t)nt * 256;
        _Pragma("unroll") for (int j = 0; j < 8; ++j) {
            int col = n_w + j * 16 + lrow;
            float bv = bias[col];
            _Pragma("unroll") for (int i = 0; i < 4; ++i)
                _Pragma("unroll") for (int r = 0; r < 4; ++r) {
                    int mrow = m_w + i * 16 + (lq << 2) + r;  // C/D: col=lane&15, row=quad*4+reg
                    float v = acc[i][j][r] + bv;
                    Hb[(size_t)mrow * FF + col] = (bf16)(v > 0.f ? v : 0.f);
                }
        }
    })
}

// ---- GEMM2: y[ks][row] = h-slice @ w2-slice (+b2 at ks==0) -> bf16, plain stores ----
__global__ __launch_bounds__(256, 3) void gemm2_kernel(const bf16* __restrict__ Hin,
                                                       const bf16* __restrict__ Bt,
                                                       const float* __restrict__ b2,
                                                       bf16* __restrict__ Y,
                                                       const int* __restrict__ counts) {
    const int e = blockIdx.z >> 2, ks = blockIdx.z & 3;
    const int mt = blockIdx.y, nt = blockIdx.x;
    const int cnt = counts[e];
    if (mt * 128 >= cnt) return;
    const int row0 = e * EROWS + mt * 128;
    const int K = FF;                      // full-K row stride
    const int KC = FF / KSPLIT2;           // 1024 per split
    const int NK = KC / 32;
    const bf16* Ab = Hin + (size_t)row0 * K + ks * KC;
    const bf16* Bb = Bt + ((size_t)e * HH + (size_t)nt * 256) * K + ks * KC;

    GEMM_BODY({
        const float* bias = b2 + (size_t)e * HH + (size_t)nt * 256;
        bf16* Yb = Y + ((size_t)ks * ROWS_CAP + row0) * HH + (size_t)nt * 256;
        _Pragma("unroll") for (int j = 0; j < 8; ++j) {
            int col = n_w + j * 16 + lrow;
            float bv = (ks == 0) ? bias[col] : 0.f;
            _Pragma("unroll") for (int i = 0; i < 4; ++i)
                _Pragma("unroll") for (int r = 0; r < 4; ++r) {
                    int mrow = m_w + i * 16 + (lq << 2) + r;
                    Yb[(size_t)mrow * HH + col] = (bf16)(acc[i][j][r] + bv);
                }
        }
    })
}

// ---- combine: out[t] = sum_slot w_slot * sum_ks y[ks][row_slot] ----
__global__ __launch_bounds__(256) void combine_kernel(const bf16* __restrict__ Y,
                                                      const int* __restrict__ rowOf,
                                                      const float* __restrict__ tkw,
                                                      float* __restrict__ out) {
    const int t = blockIdx.x;
    const int tid = threadIdx.x;
    const int ra = rowOf[t * 2 + 0], rb = rowOf[t * 2 + 1];
    const float wa = tkw[t * 2 + 0], wb = tkw[t * 2 + 1];
    const int c = tid * 4;
    float acc[4] = {0.f, 0.f, 0.f, 0.f};
#pragma unroll
    for (int ks = 0; ks < KSPLIT2; ++ks) {
        bf16x4 a = *(const bf16x4*)&Y[((size_t)ks * ROWS_CAP + ra) * HH + c];
        bf16x4 b = *(const bf16x4*)&Y[((size_t)ks * ROWS_CAP + rb) * HH + c];
#pragma unroll
        for (int k = 0; k < 4; ++k) acc[k] += wa * (float)a[k] + wb * (float)b[k];
    }
    floatx4 o; o[0] = acc[0]; o[1] = acc[1]; o[2] = acc[2]; o[3] = acc[3];
    *(floatx4*)&out[(size_t)t * HH + c] = o;
}

extern "C" void kernel_launch(void* const* d_in, const int* in_sizes, int n_in,
                              void* d_out, int out_size, void* d_ws, size_t ws_size,
                              hipStream_t stream) {
    const float* x  = (const float*)d_in[0];
    const float* gw = (const float*)d_in[1];
    const float* gb = (const float*)d_in[2];
    const float* w1 = (const float*)d_in[3];
    const float* b1 = (const float*)d_in[4];
    const float* w2 = (const float*)d_in[5];
    const float* b2 = (const float*)d_in[6];
    float* out = (float*)d_out;
    char* ws = (char*)d_ws;

    bf16*  w1t  = (bf16*)(ws + OFF_W1T);
    bf16*  w2t  = (bf16*)(ws + OFF_W2T);
    bf16*  xg   = (bf16*)(ws + OFF_XG);
    bf16*  hbuf = (bf16*)(ws + OFF_H);
    bf16*  ybuf = (bf16*)(ws + OFF_Y);     // aliases w1t (dead after gemm1)
    int*   cnts = (int*)(ws + OFF_CNT);
    float* tkw  = (float*)(ws + OFF_TKW);
    int*   rowOf= (int*)(ws + OFF_ROW);

    hipMemsetAsync(cnts, 0, 256, stream);

    router_gather<<<256, 256, 0, stream>>>(x, gw, gb, cnts, xg, rowOf, tkw);
    transpose_cvt<<<dim3(FF / 64, HH / 64, EE), 256, 0, stream>>>(w1, w1t, HH, FF);
    transpose_cvt<<<dim3(HH / 64, FF / 64, EE), 256, 0, stream>>>(w2, w2t, FF, HH);
    gemm1_kernel<<<dim3(FF / 256, 5, EE), 256, 0, stream>>>(xg, w1t, b1, hbuf, cnts);
    gemm2_kernel<<<dim3(HH / 256, 5, EE * KSPLIT2), 256, 0, stream>>>(hbuf, w2t, b2, ybuf, cnts);
    combine_kernel<<<TT, 256, 0, stream>>>(ybuf, rowOf, tkw, out);
}

// Round 6
// 484.056 us; speedup vs baseline: 1.2800x; 1.2127x over previous
//
#include <hip/hip_runtime.h>

// ---- problem dims (fixed) ----
#define TT 2048   // tokens = B*S
#define HH 1024   // hidden
#define FF 4096   // intermediate
#define EE 8      // experts
#define EROWS 640      // fixed row slots per expert (mean 512, sigma ~20 -> 6.5 sigma headroom)
#define ROWS_CAP 5120  // 8 * 640
#define KSPLIT2 4      // gemm2 split-K factor

typedef __bf16 bf16;
typedef bf16 bf16x8 __attribute__((ext_vector_type(8)));
typedef bf16 bf16x4 __attribute__((ext_vector_type(4)));
typedef float floatx4 __attribute__((ext_vector_type(4)));

// ---- workspace layout (bytes) ----
#define OFF_W1T  ((size_t)0)                       // [E][F][H] bf16 = 67108864
#define OFF_W2T  (OFF_W1T + (size_t)67108864)      // [E][H][F] bf16 = 67108864
#define OFF_XG   (OFF_W2T + (size_t)67108864)      // [ROWS_CAP][H] bf16 = 10485760
#define OFF_H    (OFF_XG  + (size_t)10485760)      // [ROWS_CAP][F] bf16 = 41943040
#define OFF_CNT  (OFF_H   + (size_t)41943040)      // int[8] (256B slot)
#define OFF_TKW  (OFF_CNT + (size_t)256)           // float[T][2]
#define OFF_ROW  (OFF_TKW + (size_t)16384)         // int[T][2] row index per (token,slot)
// Y partials [KSPLIT2][ROWS_CAP][HH] bf16 = 41943040 bytes — ALIASES w1t region:
// w1t is dead after gemm1 (stream order: transposes -> gemm1 -> gemm2 -> combine).
#define OFF_Y    OFF_W1T

// async global->LDS, 16B per lane; LDS dest is wave-uniform base + lane*16
__device__ __forceinline__ void gload16(const bf16* g, bf16* l) {
    __builtin_amdgcn_global_load_lds((const __attribute__((address_space(1))) void*)g,
                                     (__attribute__((address_space(3))) void*)l, 16, 0, 0);
}

// ---- transpose + fp32->bf16 convert: in[e][r][c] fp32 -> out[e][c][r] bf16 ----
__global__ __launch_bounds__(256) void transpose_cvt(const float* __restrict__ in,
                                                     bf16* __restrict__ out,
                                                     int R, int C) {
    __shared__ float tile[64][67];
    const int e  = blockIdx.z;
    const int r0 = blockIdx.y * 64, c0 = blockIdx.x * 64;
    const float* inp = in + (size_t)e * R * C;
    bf16* outp = out + (size_t)e * R * C;
    const int t = threadIdx.x;
    {
        const int lr = t >> 4;            // 0..15
        const int lc = (t & 15) << 2;     // 0..60 step 4
#pragma unroll
        for (int i = 0; i < 4; ++i) {
            int r = lr + i * 16;
            floatx4 v = __builtin_nontemporal_load(
                (const floatx4*)&inp[(size_t)(r0 + r) * C + c0 + lc]);
            tile[r][lc + 0] = v[0]; tile[r][lc + 1] = v[1];
            tile[r][lc + 2] = v[2]; tile[r][lc + 3] = v[3];
        }
    }
    __syncthreads();
    {
        const int c  = t >> 3;            // 0..31
        const int rq = (t & 7) << 3;      // 0..56 step 8
#pragma unroll
        for (int i = 0; i < 2; ++i) {
            int cc = c + i * 32;
            bf16x8 o;
#pragma unroll
            for (int k = 0; k < 8; ++k) o[k] = (bf16)tile[rq + k][cc];
            *(bf16x8*)&outp[(size_t)(c0 + cc) * R + r0 + rq] = o;
        }
    }
}

// ---- fused router + gather (verified body) ----
__global__ __launch_bounds__(256) void router_gather(const float* __restrict__ x,
                                                     const float* __restrict__ gw,
                                                     const float* __restrict__ gb,
                                                     int* __restrict__ counts,
                                                     bf16* __restrict__ xg,
                                                     int* __restrict__ rowOf,
                                                     float* __restrict__ tkw) {
    const int wid = blockIdx.x * 4 + (threadIdx.x >> 6);
    const int lane = threadIdx.x & 63;
    for (int t = wid; t < TT; t += 1024) {
        const float* xr = x + (size_t)t * HH;
        float xf[16];
        double acc[EE];
#pragma unroll
        for (int e = 0; e < EE; ++e) acc[e] = 0.0;
#pragma unroll
        for (int i = 0; i < 16; ++i) {
            const int h = lane + i * 64;
            const float xv = xr[h];
            xf[i] = xv;
            const float* g = gw + (size_t)h * EE;
            floatx4 g0 = *(const floatx4*)&g[0];
            floatx4 g1 = *(const floatx4*)&g[4];
            const double xd = (double)xv;
            acc[0] += xd * (double)g0[0]; acc[1] += xd * (double)g0[1];
            acc[2] += xd * (double)g0[2]; acc[3] += xd * (double)g0[3];
            acc[4] += xd * (double)g1[0]; acc[5] += xd * (double)g1[1];
            acc[6] += xd * (double)g1[2]; acc[7] += xd * (double)g1[3];
        }
#pragma unroll
        for (int e = 0; e < EE; ++e) {
            double v = acc[e];
            for (int s = 32; s > 0; s >>= 1) v += __shfl_xor(v, s, 64);
            acc[e] = v + (double)gb[e];
        }
        int row1 = 0, row2 = 0;
        if (lane == 0) {
            int i1 = 0; double v1 = acc[0];
            for (int e = 1; e < EE; ++e) if (acc[e] > v1) { v1 = acc[e]; i1 = e; }
            int i2 = -1; double v2 = -1e300;
            for (int e = 0; e < EE; ++e) if (e != i1 && acc[e] > v2) { v2 = acc[e]; i2 = e; }
            double wa = 1.0 / (1.0 + exp(v2 - v1));   // renormalized softmax of top-2
            double wb = 1.0 - wa;
            int r1 = atomicAdd(&counts[i1], 1); if (r1 > EROWS - 1) r1 = EROWS - 1;
            int r2 = atomicAdd(&counts[i2], 1); if (r2 > EROWS - 1) r2 = EROWS - 1;
            row1 = i1 * EROWS + r1;
            row2 = i2 * EROWS + r2;
            rowOf[t * 2 + 0] = row1; rowOf[t * 2 + 1] = row2;
            tkw[t * 2 + 0] = (float)wa; tkw[t * 2 + 1] = (float)wb;
        }
        row1 = __shfl(row1, 0, 64);
        row2 = __shfl(row2, 0, 64);
        bf16* d1 = xg + (size_t)row1 * HH;
        bf16* d2 = xg + (size_t)row2 * HH;
#pragma unroll
        for (int i = 0; i < 16; ++i) {
            const bf16 v = (bf16)xf[i];
            d1[lane + i * 64] = v;          // 2B/lane, lanes contiguous -> coalesced
            d2[lane + i * 64] = v;
        }
    }
}

// ================= GEMM core: m97-verified structure =================
// 128M x 128N x 32K tile, 4 waves (2Mx2N, 64x64 each), acc[4][4], 2-buffer LDS,
// plain __syncthreads() per K-step (compiler emits the vmcnt/lgkm drain), STAGE
// of tile kt+1 issued before compute of tile kt. LDS 2*(8KB A + 8KB B) = 32 KB.
// LDS byte-layout / k-oct XOR swizzle / foff frag reads carried over verbatim
// from the proven zero-conflict kernel (B tile narrowed 256->128 rows).

#define STAGE(KT, ST) do {                                                                  \
        const int kb = (KT) * 32;                                                           \
        gload16(Ab + gadr[0] + kb, (bf16*)((char*)As[ST] + ldsw));                          \
        gload16(Ab + gadr[1] + kb, (bf16*)((char*)As[ST] + 4096u + ldsw));                  \
        gload16(Bb + gadr[2] + kb, (bf16*)((char*)Bs[ST] + ldsw));                          \
        gload16(Bb + gadr[3] + kb, (bf16*)((char*)Bs[ST] + 4096u + ldsw));                  \
    } while (0)

#define GEMM_BODY(EPILOGUE)                                                                 \
    __shared__ bf16 As[2][128 * 32];                                                        \
    __shared__ bf16 Bs[2][128 * 32];                                                        \
    const int tid = threadIdx.x;                                                            \
    const int lane = tid & 63, wave = tid >> 6;                                             \
    const int lrow = lane & 15, lq = lane >> 4;                                             \
    const int m_w = (wave & 1) << 6, n_w = (wave >> 1) << 6;                                \
    const unsigned foff = (unsigned)((lq ^ ((lrow >> 1) & 3)) << 3);                        \
    floatx4 acc[4][4];                                                                      \
    _Pragma("unroll") for (int i = 0; i < 4; ++i)                                           \
        _Pragma("unroll") for (int j = 0; j < 4; ++j)                                       \
            acc[i][j] = (floatx4){0.f, 0.f, 0.f, 0.f};                                      \
    size_t gadr[4];                                                                         \
    _Pragma("unroll") for (int s = 0; s < 4; ++s) {                                         \
        int c = tid + (s & 1) * 256;                                                        \
        int ar = c >> 2, ak = (c & 3) ^ ((ar >> 1) & 3);                                    \
        gadr[s] = (size_t)ar * K + (size_t)ak * 8;                                          \
    }                                                                                       \
    const unsigned ldsw = (unsigned)((tid & ~63) << 4); /* wave*1024 bytes */               \
    /* prologue: stage tile 0 into buffer 0 */                                              \
    STAGE(0, 0);                                                                            \
    __syncthreads();                                                                        \
    for (int kt = 0; kt < NK; ++kt) {                                                       \
        const int cb = kt & 1;                                                              \
        if (kt + 1 < NK) STAGE(kt + 1, cb ^ 1);  /* async DMA to other buffer */            \
        bf16x8 af[4], bfr[4];                                                               \
        _Pragma("unroll") for (int i = 0; i < 4; ++i) {                                     \
            int m = m_w + i * 16 + lrow;                                                    \
            af[i] = *(const bf16x8*)&As[cb][(unsigned)m * 32 + foff];                       \
        }                                                                                   \
        _Pragma("unroll") for (int j = 0; j < 4; ++j) {                                     \
            int n = n_w + j * 16 + lrow;                                                    \
            bfr[j] = *(const bf16x8*)&Bs[cb][(unsigned)n * 32 + foff];                      \
        }                                                                                   \
        _Pragma("unroll") for (int i = 0; i < 4; ++i)                                       \
            _Pragma("unroll") for (int j = 0; j < 4; ++j)                                   \
                acc[i][j] = __builtin_amdgcn_mfma_f32_16x16x32_bf16(af[i], bfr[j],          \
                                                                    acc[i][j], 0, 0, 0);    \
        __syncthreads(); /* drains DMA (vmcnt0) + guards buffer reuse, m97 scheme */        \
    }                                                                                       \
    EPILOGUE

// ---- GEMM1: h = relu(xg @ w1[e] + b1[e]) -> bf16 ----
__global__ __launch_bounds__(256) void gemm1_kernel(const bf16* __restrict__ A,
                                                    const bf16* __restrict__ Bt,
                                                    const float* __restrict__ b1,
                                                    bf16* __restrict__ Hout,
                                                    const int* __restrict__ counts) {
    const int e = blockIdx.z, mt = blockIdx.y, nt = blockIdx.x;
    const int cnt = counts[e];
    if (mt * 128 >= cnt) return;
    const int row0 = e * EROWS + mt * 128;
    const int K = HH;
    const int NK = K / 32;
    const bf16* Ab = A + (size_t)row0 * K;
    const bf16* Bb = Bt + ((size_t)e * FF + (size_t)nt * 128) * K;

    GEMM_BODY({
        const float* bias = b1 + (size_t)e * FF + (size_t)nt * 128;
        bf16* Hb = Hout + (size_t)row0 * FF + (size_t)nt * 128;
        _Pragma("unroll") for (int j = 0; j < 4; ++j) {
            int col = n_w + j * 16 + lrow;
            float bv = bias[col];
            _Pragma("unroll") for (int i = 0; i < 4; ++i)
                _Pragma("unroll") for (int r = 0; r < 4; ++r) {
                    int mrow = m_w + i * 16 + (lq << 2) + r;  // C/D: col=lane&15, row=quad*4+reg
                    float v = acc[i][j][r] + bv;
                    Hb[(size_t)mrow * FF + col] = (bf16)(v > 0.f ? v : 0.f);
                }
        }
    })
}

// ---- GEMM2: y[ks][row] = h-slice @ w2-slice (+b2 at ks==0) -> bf16, plain stores ----
__global__ __launch_bounds__(256) void gemm2_kernel(const bf16* __restrict__ Hin,
                                                    const bf16* __restrict__ Bt,
                                                    const float* __restrict__ b2,
                                                    bf16* __restrict__ Y,
                                                    const int* __restrict__ counts) {
    const int e = blockIdx.z >> 2, ks = blockIdx.z & 3;
    const int mt = blockIdx.y, nt = blockIdx.x;
    const int cnt = counts[e];
    if (mt * 128 >= cnt) return;
    const int row0 = e * EROWS + mt * 128;
    const int K = FF;                      // full-K row stride
    const int KC = FF / KSPLIT2;           // 1024 per split
    const int NK = KC / 32;
    const bf16* Ab = Hin + (size_t)row0 * K + ks * KC;
    const bf16* Bb = Bt + ((size_t)e * HH + (size_t)nt * 128) * K + ks * KC;

    GEMM_BODY({
        const float* bias = b2 + (size_t)e * HH + (size_t)nt * 128;
        bf16* Yb = Y + ((size_t)ks * ROWS_CAP + row0) * HH + (size_t)nt * 128;
        _Pragma("unroll") for (int j = 0; j < 4; ++j) {
            int col = n_w + j * 16 + lrow;
            float bv = (ks == 0) ? bias[col] : 0.f;
            _Pragma("unroll") for (int i = 0; i < 4; ++i)
                _Pragma("unroll") for (int r = 0; r < 4; ++r) {
                    int mrow = m_w + i * 16 + (lq << 2) + r;
                    Yb[(size_t)mrow * HH + col] = (bf16)(acc[i][j][r] + bv);
                }
        }
    })
}

// ---- combine: out[t] = sum_slot w_slot * sum_ks y[ks][row_slot] ----
__global__ __launch_bounds__(256) void combine_kernel(const bf16* __restrict__ Y,
                                                      const int* __restrict__ rowOf,
                                                      const float* __restrict__ tkw,
                                                      float* __restrict__ out) {
    const int t = blockIdx.x;
    const int tid = threadIdx.x;
    const int ra = rowOf[t * 2 + 0], rb = rowOf[t * 2 + 1];
    const float wa = tkw[t * 2 + 0], wb = tkw[t * 2 + 1];
    const int c = tid * 4;
    float acc[4] = {0.f, 0.f, 0.f, 0.f};
#pragma unroll
    for (int ks = 0; ks < KSPLIT2; ++ks) {
        bf16x4 a = *(const bf16x4*)&Y[((size_t)ks * ROWS_CAP + ra) * HH + c];
        bf16x4 b = *(const bf16x4*)&Y[((size_t)ks * ROWS_CAP + rb) * HH + c];
#pragma unroll
        for (int k = 0; k < 4; ++k) acc[k] += wa * (float)a[k] + wb * (float)b[k];
    }
    floatx4 o; o[0] = acc[0]; o[1] = acc[1]; o[2] = acc[2]; o[3] = acc[3];
    *(floatx4*)&out[(size_t)t * HH + c] = o;
}

extern "C" void kernel_launch(void* const* d_in, const int* in_sizes, int n_in,
                              void* d_out, int out_size, void* d_ws, size_t ws_size,
                              hipStream_t stream) {
    const float* x  = (const float*)d_in[0];
    const float* gw = (const float*)d_in[1];
    const float* gb = (const float*)d_in[2];
    const float* w1 = (const float*)d_in[3];
    const float* b1 = (const float*)d_in[4];
    const float* w2 = (const float*)d_in[5];
    const float* b2 = (const float*)d_in[6];
    float* out = (float*)d_out;
    char* ws = (char*)d_ws;

    bf16*  w1t  = (bf16*)(ws + OFF_W1T);
    bf16*  w2t  = (bf16*)(ws + OFF_W2T);
    bf16*  xg   = (bf16*)(ws + OFF_XG);
    bf16*  hbuf = (bf16*)(ws + OFF_H);
    bf16*  ybuf = (bf16*)(ws + OFF_Y);     // aliases w1t (dead after gemm1)
    int*   cnts = (int*)(ws + OFF_CNT);
    float* tkw  = (float*)(ws + OFF_TKW);
    int*   rowOf= (int*)(ws + OFF_ROW);

    hipMemsetAsync(cnts, 0, 256, stream);

    router_gather<<<256, 256, 0, stream>>>(x, gw, gb, cnts, xg, rowOf, tkw);
    transpose_cvt<<<dim3(FF / 64, HH / 64, EE), 256, 0, stream>>>(w1, w1t, HH, FF);
    transpose_cvt<<<dim3(HH / 64, FF / 64, EE), 256, 0, stream>>>(w2, w2t, FF, HH);
    gemm1_kernel<<<dim3(FF / 128, 5, EE), 256, 0, stream>>>(xg, w1t, b1, hbuf, cnts);
    gemm2_kernel<<<dim3(HH / 128, 5, EE * KSPLIT2), 256, 0, stream>>>(hbuf, w2t, b2, ybuf, cnts);
    combine_kernel<<<TT, 256, 0, stream>>>(ybuf, rowOf, tkw, out);
}